// Round 1
// baseline (364.167 us; speedup 1.0000x reference)
//
#include <hip/hip_runtime.h>
#include <math.h>

// FastTensorSRHT: out[b,f] = scale * prod_d FWHT(x[b]*rad[d])[perm[d,f]]
// B=16384, D_IN=1024, DEGREE=4, D_FEATURES=4096, out f32.
//
// One block per batch row. 256 threads = 4 waves; wave w computes the FWHT
// for degree w fully (1024 elems, 16 per lane).
// FWHT-1024 decomposition (stages commute):
//   round 1: bits 0-3 in registers (radix-16)
//   LDS transpose (17-pad rows -> conflict-free-ish)
//   round 2: bits 6-9 in registers (radix-16)
//   round 3: bits 4-5 across lanes via DPP quad_perm (VALU, no LDS)
// Then ybuf[4][1024] in LDS, block barrier, random gather-product phase.

#define D_IN_N 1024
#define D_FEAT 4096

template <int CTRL>
__device__ __forceinline__ float dpp_xor(float x) {
  int r = __builtin_amdgcn_mov_dpp(__float_as_int(x), CTRL, 0xF, 0xF, true);
  return __int_as_float(r);
}

__global__ __launch_bounds__(256, 4) void srht_kernel(
    const float* __restrict__ x,
    const float* __restrict__ rad,
    const int*  __restrict__ perms,
    const float* __restrict__ log_ls,
    const float* __restrict__ log_var,
    float* __restrict__ out)
{
  __shared__ float stage[4][64 * 17];   // 17-float pad: write banks 2-way (free)
  __shared__ float ybuf[4][D_IN_N];     // gather source

  const int tid = threadIdx.x;
  const int w = tid >> 6;               // wave id == degree id
  const int l = tid & 63;               // lane
  const long long b = blockIdx.x;       // batch row

  // ---- round 1: load x*rad (64B/lane, coalesced), FWHT bits 0-3 ----
  const float4* x4 = reinterpret_cast<const float4*>(x + b * D_IN_N);
  const float4* r4 = reinterpret_cast<const float4*>(rad + (long long)w * D_IN_N);
  float v[16];
#pragma unroll
  for (int q = 0; q < 4; ++q) {
    float4 xa = x4[l * 4 + q];
    float4 ra = r4[l * 4 + q];
    v[4 * q + 0] = xa.x * ra.x;
    v[4 * q + 1] = xa.y * ra.y;
    v[4 * q + 2] = xa.z * ra.z;
    v[4 * q + 3] = xa.w * ra.w;
  }
#pragma unroll
  for (int h = 1; h < 16; h <<= 1) {
#pragma unroll
    for (int m = 0; m < 16; ++m) {
      if (!(m & h)) {
        float va = v[m], vb = v[m + h];
        v[m] = va + vb;
        v[m + h] = va - vb;
      }
    }
  }

  // element idx = l*16 + m  ->  stage[w][l*17 + m]
#pragma unroll
  for (int m = 0; m < 16; ++m) stage[w][l * 17 + m] = v[m];
  __syncthreads();

  // ---- round 2: thread (a = l>>2 -> bits0-3, c = l&3 -> bits4-5),
  //      regs hold bits 6-9.  idx = a + 16c + 64*m2
  //      stage addr: (idx>>4)*17 + (idx&15) = (c + 4*m2)*17 + a
  const int c = l & 3;
  const int a = l >> 2;
#pragma unroll
  for (int m2 = 0; m2 < 16; ++m2) v[m2] = stage[w][(c + 4 * m2) * 17 + a];
#pragma unroll
  for (int h = 1; h < 16; h <<= 1) {
#pragma unroll
    for (int m = 0; m < 16; ++m) {
      if (!(m & h)) {
        float va = v[m], vb = v[m + h];
        v[m] = va + vb;
        v[m + h] = va - vb;
      }
    }
  }

  // ---- round 3: bits 4,5 == lane bits 0,1 -> DPP quad_perm xor1 / xor2 ----
#pragma unroll
  for (int m = 0; m < 16; ++m) {
    float o = dpp_xor<0xB1>(v[m]);                 // lane ^ 1
    v[m] = (l & 1) ? (o - v[m]) : (v[m] + o);
  }
#pragma unroll
  for (int m = 0; m < 16; ++m) {
    float o = dpp_xor<0x4E>(v[m]);                 // lane ^ 2
    v[m] = (l & 2) ? (o - v[m]) : (v[m] + o);
  }

  // final write: idx = a + 16c + 64*m ; banks (a+16c)%32 -> exactly 2-way, free
#pragma unroll
  for (int m = 0; m < 16; ++m) ybuf[w][a + 16 * c + 64 * m] = v[m];
  __syncthreads();

  // ---- gather/product phase ----
  // scale folds: x/exp(ll) appears once per degree (linear) -> exp(-4*ll);
  // exp(lv/2); 1/sqrt(4096) = 1/64.
  const float scale = expf(0.5f * log_var[0] - 4.0f * log_ls[0]) * (1.0f / 64.0f);

  const int4* pm = reinterpret_cast<const int4*>(perms);  // [4][1024] int4
  float4* out4 = reinterpret_cast<float4*>(out + b * D_FEAT);
#pragma unroll
  for (int seg = 0; seg < 4; ++seg) {
    int fi = seg * 256 + tid;         // float4 index into this row's output
    int4 p0 = pm[0 * 1024 + fi];
    int4 p1 = pm[1 * 1024 + fi];
    int4 p2 = pm[2 * 1024 + fi];
    int4 p3 = pm[3 * 1024 + fi];
    float4 o;
    o.x = ybuf[0][p0.x] * ybuf[1][p1.x] * ybuf[2][p2.x] * ybuf[3][p3.x] * scale;
    o.y = ybuf[0][p0.y] * ybuf[1][p1.y] * ybuf[2][p2.y] * ybuf[3][p3.y] * scale;
    o.z = ybuf[0][p0.z] * ybuf[1][p1.z] * ybuf[2][p2.z] * ybuf[3][p3.z] * scale;
    o.w = ybuf[0][p0.w] * ybuf[1][p1.w] * ybuf[2][p2.w] * ybuf[3][p3.w] * scale;
    out4[fi] = o;
  }
}

extern "C" void kernel_launch(void* const* d_in, const int* in_sizes, int n_in,
                              void* d_out, int out_size, void* d_ws, size_t ws_size,
                              hipStream_t stream) {
  const float* x      = (const float*)d_in[0];
  const float* rad    = (const float*)d_in[1];
  const int*   perms  = (const int*)d_in[2];
  const float* lls    = (const float*)d_in[3];
  const float* lv     = (const float*)d_in[4];
  float* out          = (float*)d_out;

  const int batch = in_sizes[0] / D_IN_N;   // 16384
  srht_kernel<<<batch, 256, 0, stream>>>(x, rad, perms, lls, lv, out);
}